// Round 4
// baseline (187.956 us; speedup 1.0000x reference)
//
#include <hip/hip_runtime.h>
#include <hip/hip_bf16.h>
#include <math.h>

// FeedForwardQuantum — bf16 MFMA, barrier-free K-loop.
//
// Quantum layer closed form: c_w = cos(x[n,w]+rx[w]);
//   q[n,0] = prod_{1..9} c;  q[n,w] = prod_{0..w} c.
// h   = relu(q @ w1^T + b1)   GEMM1, K=10 padded to 32 (MFMA, operands
//                             SWAPPED: mfma(w1,qT) -> h^T in C-layout)
// out = h @ w2^T + b2         GEMM2, M=16384 K=2048 N=512 (MFMA)
//
// Structure: 128x128 C-tile, 4 waves of 64x64. Each wave computes GEMM1 for
// its own 64 tokens (duplicated across the wn-twin) and round-trips h^T
// through a WAVE-PRIVATE double-buffered LDS slice -> no __syncthreads in
// the K-loop (producer == consumer wave; lgkmcnt orders it). h^T commit =
// 8x ds_write_b64, A-frag read = 4x ds_read_b128, both conflict-free via
// k-block XOR swizzle: blk_stored = blk ^ (((token>>1)&3)<<1).

typedef __attribute__((ext_vector_type(8))) short short8;
typedef __attribute__((ext_vector_type(4))) float fx4;

constexpr int EDIM = 512;
constexpr int FDIM = 2048;
constexpr int NQ   = 10;
constexpr int BM   = 128;
constexpr int BK   = 32;
constexpr int NT   = 256;          // 4 waves
constexpr int NCH  = FDIM / BK;    // 64 chunks

__device__ __forceinline__ ushort f2bf(float f) {   // f32 -> bf16 RNE
    union { float f; unsigned u; } v; v.f = f;
    unsigned u = v.u + 0x7FFFu + ((v.u >> 16) & 1u);
    return (ushort)(u >> 16);
}
__device__ __forceinline__ unsigned bits2(__hip_bfloat162 h) {
    union { __hip_bfloat162 h; unsigned u; } v; v.h = h; return v.u;
}

// ---- prep: w2 f32 -> bf16; w1 -> [FDIM][32] bf16 zero-padded ----
__global__ void prep(const float* __restrict__ w1, const float* __restrict__ w2,
                     ushort* __restrict__ w2b, ushort* __restrict__ w1p) {
    int gid = blockIdx.x * blockDim.x + threadIdx.x;
    int np  = gridDim.x * blockDim.x;
    for (int i = gid; i < EDIM * FDIM / 4; i += np) {
        float4 v = ((const float4*)w2)[i];
        ushort4 o; o.x = f2bf(v.x); o.y = f2bf(v.y); o.z = f2bf(v.z); o.w = f2bf(v.w);
        ((ushort4*)w2b)[i] = o;
    }
    for (int i = gid; i < FDIM * 32; i += np) {
        int r = i >> 5, c = i & 31;
        w1p[i] = (c < NQ) ? f2bf(w1[r * NQ + c]) : (ushort)0;
    }
}

__global__ __launch_bounds__(NT, 2) void ffq(
    const float* __restrict__ x,
    const float* __restrict__ rx,
    const float* __restrict__ b1,
    const float* __restrict__ b2,
    const ushort* __restrict__ w2b,   // [EDIM][FDIM] bf16
    const ushort* __restrict__ w1p,   // [FDIM][32] bf16, cols 10..31 = 0
    float* __restrict__ out)
{
    __shared__ ushort qs[BM * 32];          // 8 KB, q padded to K=32
    __shared__ ushort As[2 * 4 * 64 * 32];  // 32 KB: [buf][wave][tok 64][k 32]

    const int tid  = threadIdx.x;
    const int bm   = blockIdx.x & 127, bn = blockIdx.x >> 7;
    const int m0   = bm * BM, n0 = bn * 128;
    const int wave = tid >> 6, lane = tid & 63;
    const int quad = lane >> 4, l16 = lane & 15;
    const int wm   = wave >> 1, wn = wave & 1;

    // ---- preamble: closed-form quantum layer -> qs (the ONLY barrier) ----
    if (tid < BM) {
        const float* xr = x + (size_t)(m0 + tid) * EDIM;
        float c[NQ], q[NQ];
        #pragma unroll
        for (int w = 0; w < NQ; ++w) c[w] = cosf(xr[w] + rx[w]);
        float p0 = c[1];
        #pragma unroll
        for (int w = 2; w < NQ; ++w) p0 *= c[w];
        q[0] = p0;
        float p = c[0];
        #pragma unroll
        for (int w = 1; w < NQ; ++w) { p *= c[w]; q[w] = p; }
        ushort* row = &qs[tid * 32];
        #pragma unroll
        for (int w = 0; w < NQ; ++w) row[w] = f2bf(q[w]);
        #pragma unroll
        for (int w = NQ; w < 32; ++w) row[w] = 0;
    }
    __syncthreads();

    // persistent q^T B-frags (B[k=quad*8+j][n=token=l16]) for this wave's 64 tokens
    short8 qf[4];
    #pragma unroll
    for (int tt = 0; tt < 4; ++tt)
        qf[tt] = *(const short8*)&qs[((wm * 64 + tt * 16 + l16) << 5) + (quad << 3)];

    // global frag bases
    const ushort* bbase = w2b + (size_t)(n0 + wn * 64 + l16) * FDIM + (quad << 3);
    const ushort* w1b   = w1p + (l16 << 5) + (quad << 3);

    // wave-private LDS slice offsets (ushort units)
    const int wsl  = wave * 2048;
    const int swm  = ((l16 >> 1) & 3) << 1;                       // write swizzle mask
    const int wo0  = wsl + (l16 << 5) + (((0 + quad) ^ swm) << 2); // s=0 blk=quad
    const int wo1  = wsl + (l16 << 5) + (((4 + quad) ^ swm) << 2); // s=1 blk=4+quad
    const int ro   = wsl + (l16 << 5) + ((quad ^ ((l16 >> 1) & 3)) << 3);

    fx4 acc[4][4];
    #pragma unroll
    for (int a = 0; a < 4; ++a)
        #pragma unroll
        for (int b = 0; b < 4; ++b) acc[a][b] = fx4{0.f, 0.f, 0.f, 0.f};

    // ---- GEMM1 chunk 0 -> As buf0 ----
    short8 w1f[2]; fx4 b1v[2];
    #pragma unroll
    for (int s = 0; s < 2; ++s) {
        w1f[s] = *(const short8*)&w1b[(s * 16) << 5];
        b1v[s] = *(const fx4*)&b1[s * 16 + (quad << 2)];
    }
    #pragma unroll
    for (int tt = 0; tt < 4; ++tt)
        #pragma unroll
        for (int s = 0; s < 2; ++s) {
            fx4 h = __builtin_amdgcn_mfma_f32_16x16x32_bf16(w1f[s], qf[tt], b1v[s], 0, 0, 0);
            uint2 pk;
            pk.x = bits2(__float22bfloat162_rn(make_float2(fmaxf(h[0], 0.f), fmaxf(h[1], 0.f))));
            pk.y = bits2(__float22bfloat162_rn(make_float2(fmaxf(h[2], 0.f), fmaxf(h[3], 0.f))));
            *(uint2*)&As[(s ? wo1 : wo0) + tt * 512] = pk;
        }

    // ---- prefetch: B-frags chunk 0, w1/b1 chunk 1 ----
    short8 bf[4];
    #pragma unroll
    for (int nt = 0; nt < 4; ++nt)
        bf[nt] = *(const short8*)&bbase[(size_t)nt * 16 * FDIM];
    #pragma unroll
    for (int s = 0; s < 2; ++s) {
        w1f[s] = *(const short8*)&w1b[(BK + s * 16) << 5];
        b1v[s] = *(const fx4*)&b1[BK + s * 16 + (quad << 2)];
    }

    // ---- barrier-free K-loop ----
    #pragma unroll 2
    for (int i = 0; i < NCH; ++i) {
        const int buf  = (i & 1) << 13;    // *8192 ushorts
        const int nbuf = buf ^ 8192;

        // A-frags of chunk i (written last iteration; same-wave lgkm ordering)
        short8 af[4];
        #pragma unroll
        for (int mt = 0; mt < 4; ++mt)
            af[mt] = *(const short8*)&As[buf + ro + mt * 512];

        // GEMM1 chunk i+1 -> nbuf (b64 writes, swizzled, conflict-free)
        #pragma unroll
        for (int tt = 0; tt < 4; ++tt)
            #pragma unroll
            for (int s = 0; s < 2; ++s) {
                fx4 h = __builtin_amdgcn_mfma_f32_16x16x32_bf16(w1f[s], qf[tt], b1v[s], 0, 0, 0);
                uint2 pk;
                pk.x = bits2(__float22bfloat162_rn(make_float2(fmaxf(h[0], 0.f), fmaxf(h[1], 0.f))));
                pk.y = bits2(__float22bfloat162_rn(make_float2(fmaxf(h[2], 0.f), fmaxf(h[3], 0.f))));
                *(uint2*)&As[nbuf + (s ? wo1 : wo0) + tt * 512] = pk;
            }

        // global prefetch (consumed next iteration; clamps keep OOB-safe,
        // clamped iterations produce values that are never read)
        const int kb = min((i + 1) * BK, FDIM - BK);   // B-frags chunk i+1
        const int k2 = min((i + 2) * BK, FDIM - BK);   // w1/b1 chunk i+2
        short8 bfn[4], w1fn[2]; fx4 b1vn[2];
        #pragma unroll
        for (int nt = 0; nt < 4; ++nt)
            bfn[nt] = *(const short8*)&bbase[(size_t)nt * 16 * FDIM + kb];
        #pragma unroll
        for (int s = 0; s < 2; ++s) {
            w1fn[s] = *(const short8*)&w1b[(k2 + s * 16) << 5];
            b1vn[s] = *(const fx4*)&b1[k2 + s * 16 + (quad << 2)];
        }

        // GEMM2 chunk i
        #pragma unroll
        for (int mt = 0; mt < 4; ++mt)
            #pragma unroll
            for (int nt = 0; nt < 4; ++nt)
                acc[mt][nt] = __builtin_amdgcn_mfma_f32_16x16x32_bf16(
                    af[mt], bf[nt], acc[mt][nt], 0, 0, 0);

        #pragma unroll
        for (int nt = 0; nt < 4; ++nt) bf[nt] = bfn[nt];
        #pragma unroll
        for (int s = 0; s < 2; ++s) { w1f[s] = w1fn[s]; b1v[s] = b1vn[s]; }
    }

    // ---- epilogue: + b2, C-layout stores (col=l16 -> n, row=quad*4+r -> m) ----
    float bb[4];
    #pragma unroll
    for (int nt = 0; nt < 4; ++nt) bb[nt] = b2[n0 + wn * 64 + nt * 16 + l16];
    #pragma unroll
    for (int mt = 0; mt < 4; ++mt) {
        const int mbase = m0 + wm * 64 + mt * 16 + (quad << 2);
        #pragma unroll
        for (int nt = 0; nt < 4; ++nt) {
            const int n = n0 + wn * 64 + nt * 16 + l16;
            #pragma unroll
            for (int r = 0; r < 4; ++r)
                out[(size_t)(mbase + r) * EDIM + n] = acc[mt][nt][r] + bb[nt];
        }
    }
}

extern "C" void kernel_launch(void* const* d_in, const int* in_sizes, int n_in,
                              void* d_out, int out_size, void* d_ws, size_t ws_size,
                              hipStream_t stream) {
    const float* x  = (const float*)d_in[0];
    const float* rx = (const float*)d_in[1];
    const float* w1 = (const float*)d_in[2];
    const float* b1 = (const float*)d_in[3];
    const float* w2 = (const float*)d_in[4];
    const float* b2 = (const float*)d_in[5];
    float* out = (float*)d_out;

    ushort* w2b = (ushort*)d_ws;
    ushort* w1p = (ushort*)((char*)d_ws + (size_t)EDIM * FDIM * 2);

    hipLaunchKernelGGL(prep, dim3(1024), dim3(256), 0, stream, w1, w2, w2b, w1p);

    const int M = in_sizes[0] / EDIM;                 // 16384
    dim3 grid((M / BM) * (EDIM / 128)), block(NT);    // 512 blocks
    hipLaunchKernelGGL(ffq, grid, block, 0, stream,
                       x, rx, b1, b2, w2b, w1p, out);
}

// Round 5
// 154.089 us; speedup vs baseline: 1.2198x; 1.2198x over previous
//
#include <hip/hip_runtime.h>
#include <hip/hip_bf16.h>
#include <math.h>

// FeedForwardQuantum — decoupled: closed-form quantum layer + fp32 GEMM1 -> h
// (bf16, in d_ws), then m97-recipe bf16 MFMA GEMM2 (global_load_lds staging).
//
// q closed form: c_w = cos(x[n,w]+rx[w]); q[n,0]=prod_{1..9}c; q[n,w]=prod_{0..w}c
// h   = relu(q @ w1^T + b1)        [fp32 VALU, 10 FMA/elem, bf16 out]
// out = h @ w2^T + b2              [MFMA 16x16x32 bf16, 128x128 tile, BK=32,
//                                   both tiles staged via global_load_lds w=16]

typedef __attribute__((ext_vector_type(8))) short short8;
typedef __attribute__((ext_vector_type(8))) unsigned short ushort8;
typedef __attribute__((ext_vector_type(4))) float fx4;

constexpr int EDIM = 512;
constexpr int FDIM = 2048;
constexpr int NQ   = 10;
constexpr int BK   = 32;
constexpr int NCH  = FDIM / BK;   // 64

__device__ __forceinline__ ushort f2bf(float f) {   // f32 -> bf16 RNE
    union { float f; unsigned u; } v; v.f = f;
    unsigned u = v.u + 0x7FFFu + ((v.u >> 16) & 1u);
    return (ushort)(u >> 16);
}
__device__ __forceinline__ unsigned bits2(__hip_bfloat162 h) {
    union { __hip_bfloat162 h; unsigned u; } v; v.h = h; return v.u;
}
__device__ __forceinline__ void gload_lds16(const void* g, void* l) {
    __builtin_amdgcn_global_load_lds(
        (const __attribute__((address_space(1))) void*)g,
        (__attribute__((address_space(3))) void*)l, 16, 0, 0);
}

// ---- prep: w2 f32 -> bf16 ----
__global__ void prep(const float* __restrict__ w2, ushort* __restrict__ w2b) {
    int gid = blockIdx.x * blockDim.x + threadIdx.x;
    int np  = gridDim.x * blockDim.x;
    for (int i = gid; i < EDIM * FDIM / 4; i += np) {
        float4 v = ((const float4*)w2)[i];
        ushort4 o; o.x = f2bf(v.x); o.y = f2bf(v.y); o.z = f2bf(v.z); o.w = f2bf(v.w);
        ((ushort4*)w2b)[i] = o;
    }
}

// ---- GEMM1: h[m][f] = relu(sum_w q[m][w]*w1[f][w] + b1[f]), bf16 out ----
// Block: 32 tokens x all 2048 f. Thread t owns f-slice [8t, 8t+8): w1 slice
// (80 contiguous floats) lives in registers, read once per block from L2.
__global__ __launch_bounds__(256, 2) void gemm1(
    const float* __restrict__ x, const float* __restrict__ rx,
    const float* __restrict__ w1, const float* __restrict__ b1,
    ushort* __restrict__ h, int m_base)
{
    __shared__ float qs[32][NQ];
    const int tid = threadIdx.x;
    const int m0  = m_base + blockIdx.x * 32;

    if (tid < 32) {
        const float* xr = x + (size_t)(m0 + tid) * EDIM;
        float c[NQ], q[NQ];
        #pragma unroll
        for (int w = 0; w < NQ; ++w) c[w] = cosf(xr[w] + rx[w]);
        float p0 = c[1];
        #pragma unroll
        for (int w = 2; w < NQ; ++w) p0 *= c[w];
        q[0] = p0;
        float p = c[0];
        #pragma unroll
        for (int w = 1; w < NQ; ++w) { p *= c[w]; q[w] = p; }
        #pragma unroll
        for (int w = 0; w < NQ; ++w) qs[tid][w] = q[w];
    }
    __syncthreads();

    float wv[80];   // w1 rows [8t, 8t+8), 10 floats each, contiguous
    {
        const float4* wp = (const float4*)(w1 + (size_t)tid * 80);  // 320B-aligned
        #pragma unroll
        for (int u = 0; u < 20; ++u) ((float4*)wv)[u] = wp[u];
    }
    float bv[8];
    {
        float4 a = *(const float4*)(b1 + tid * 8);
        float4 b = *(const float4*)(b1 + tid * 8 + 4);
        bv[0]=a.x; bv[1]=a.y; bv[2]=a.z; bv[3]=a.w;
        bv[4]=b.x; bv[5]=b.y; bv[6]=b.z; bv[7]=b.w;
    }
    ushort* hrow = h + (size_t)m0 * FDIM + tid * 8;

    for (int m = 0; m < 32; ++m) {
        float qv[NQ];
        #pragma unroll
        for (int w = 0; w < NQ; ++w) qv[w] = qs[m][w];   // LDS broadcast
        float a[8];
        #pragma unroll
        for (int r = 0; r < 8; ++r) a[r] = bv[r];
        #pragma unroll
        for (int w = 0; w < NQ; ++w)
            #pragma unroll
            for (int r = 0; r < 8; ++r)
                a[r] = fmaf(qv[w], wv[r * 10 + w], a[r]);
        ushort8 o;
        #pragma unroll
        for (int r = 0; r < 4; ++r) {
            unsigned p = bits2(__float22bfloat162_rn(
                make_float2(fmaxf(a[2*r], 0.f), fmaxf(a[2*r+1], 0.f))));
            o[2*r]   = (ushort)(p & 0xFFFFu);
            o[2*r+1] = (ushort)(p >> 16);
        }
        *(ushort8*)(hrow + (size_t)m * FDIM) = o;        // 16B coalesced store
    }
}

// ---- GEMM2: out = h @ w2^T + b2 — m97 recipe ----
__global__ __launch_bounds__(256, 3) void gemm2(
    const ushort* __restrict__ h,     // [M][FDIM] bf16
    const ushort* __restrict__ w2b,   // [EDIM][FDIM] bf16
    const float* __restrict__ b2,
    float* __restrict__ out, int m_base)
{
    __shared__ ushort As[128 * BK];   // 8 KB, row-major [row][k], 64B rows
    __shared__ ushort Bs[128 * BK];   // 8 KB

    const int tid  = threadIdx.x;
    const int bm   = blockIdx.x >> 2, bn = blockIdx.x & 3;
    const int m0   = m_base + bm * 128, n0 = bn * 128;
    const int wave = tid >> 6, lane = tid & 63;
    const int quad = lane >> 4, l16 = lane & 15;
    const int wm   = wave >> 1, wn = wave & 1;

    // staging addresses: thread t -> row t>>2, 16B segment t&3 (per j half)
    const ushort* ga0 = h  + (size_t)(m0 + (tid >> 2)) * FDIM + (tid & 3) * 8;
    const ushort* ga1 = ga0 + (size_t)64 * FDIM;
    const ushort* gb0 = w2b + (size_t)(n0 + (tid >> 2)) * FDIM + (tid & 3) * 8;
    const ushort* gb1 = gb0 + (size_t)64 * FDIM;
    ushort* lA0 = &As[wave * 512];          // wave-uniform base + lane*16B
    ushort* lA1 = &As[2048 + wave * 512];
    ushort* lB0 = &Bs[wave * 512];
    ushort* lB1 = &Bs[2048 + wave * 512];

    const int aro = (wm * 64 + l16) * BK + quad * 8;   // A-frag LDS offset
    const int bro = (wn * 64 + l16) * BK + quad * 8;   // B-frag LDS offset

    fx4 acc[4][4];
    #pragma unroll
    for (int a = 0; a < 4; ++a)
        #pragma unroll
        for (int b = 0; b < 4; ++b) acc[a][b] = fx4{0.f, 0.f, 0.f, 0.f};

    for (int i = 0; i < NCH; ++i) {
        gload_lds16(ga0, lA0);  gload_lds16(ga1, lA1);
        gload_lds16(gb0, lB0);  gload_lds16(gb1, lB1);
        ga0 += BK; ga1 += BK; gb0 += BK; gb1 += BK;
        __syncthreads();                         // drains vmcnt -> tiles ready

        short8 af[4], bf[4];
        #pragma unroll
        for (int mt = 0; mt < 4; ++mt) af[mt] = *(const short8*)&As[aro + mt * 16 * BK];
        #pragma unroll
        for (int nt = 0; nt < 4; ++nt) bf[nt] = *(const short8*)&Bs[bro + nt * 16 * BK];

        #pragma unroll
        for (int mt = 0; mt < 4; ++mt)
            #pragma unroll
            for (int nt = 0; nt < 4; ++nt)
                acc[mt][nt] = __builtin_amdgcn_mfma_f32_16x16x32_bf16(
                    af[mt], bf[nt], acc[mt][nt], 0, 0, 0);
        __syncthreads();                         // protect tiles from next stage
    }

    // epilogue: + b2, C-layout (col=l16 -> n, row=quad*4+r -> m)
    float bb[4];
    #pragma unroll
    for (int nt = 0; nt < 4; ++nt) bb[nt] = b2[n0 + wn * 64 + nt * 16 + l16];
    #pragma unroll
    for (int mt = 0; mt < 4; ++mt) {
        const int mbase = m0 + wm * 64 + mt * 16 + quad * 4;
        #pragma unroll
        for (int nt = 0; nt < 4; ++nt) {
            const int n = n0 + wn * 64 + nt * 16 + l16;
            #pragma unroll
            for (int r = 0; r < 4; ++r)
                out[(size_t)(mbase + r) * EDIM + n] = acc[mt][nt][r] + bb[nt];
        }
    }
}

extern "C" void kernel_launch(void* const* d_in, const int* in_sizes, int n_in,
                              void* d_out, int out_size, void* d_ws, size_t ws_size,
                              hipStream_t stream) {
    const float* x  = (const float*)d_in[0];
    const float* rx = (const float*)d_in[1];
    const float* w1 = (const float*)d_in[2];
    const float* b1 = (const float*)d_in[3];
    const float* w2 = (const float*)d_in[4];
    const float* b2 = (const float*)d_in[5];
    float* out = (float*)d_out;

    const int M = in_sizes[0] / EDIM;   // 16384

    // ws layout: [0, 2 MiB) w2 bf16; [2 MiB, ...) h bf16 slice
    const size_t w2bytes = (size_t)EDIM * FDIM * 2;
    ushort* w2b = (ushort*)d_ws;
    ushort* h   = (ushort*)((char*)d_ws + w2bytes);

    // slice M so the h slice fits in ws (full M needs 64 MiB)
    int Ms = M;
    {
        size_t avail = (ws_size > w2bytes) ? ws_size - w2bytes : 0;
        int cap = (int)(avail / ((size_t)FDIM * 2));
        cap &= ~127;
        if (cap < 128) cap = 128;       // assume ws at least this big
        if (Ms > cap) Ms = cap;
    }

    hipLaunchKernelGGL(prep, dim3(256), dim3(256), 0, stream, w2, w2b);

    for (int mb = 0; mb < M; mb += Ms) {
        int cur = (M - mb < Ms) ? (M - mb) : Ms;
        hipLaunchKernelGGL(gemm1, dim3(cur / 32), dim3(256), 0, stream,
                           x, rx, w1, b1, h, mb);
        hipLaunchKernelGGL(gemm2, dim3((cur / 128) * 4), dim3(256), 0, stream,
                           h, w2b, b2, out, mb);
    }
}

// Round 6
// 139.876 us; speedup vs baseline: 1.3437x; 1.1016x over previous
//
#include <hip/hip_runtime.h>
#include <hip/hip_bf16.h>
#include <math.h>

// FeedForwardQuantum — decoupled: closed-form quantum layer + fp32 GEMM1 -> h
// (bf16 in d_ws), then m97-recipe bf16 MFMA GEMM2.
// Round 6: XCD-grouped grid (n-twins share an XCD's L2 for the h tile),
// BK=64 (2x MFMA per barrier), global-side XOR swizzle (conflict-free-ish
// b128 frag reads; swizzle lives in the *global* address since
// global_load_lds forces contiguous lane->LDS mapping).

typedef __attribute__((ext_vector_type(8))) short short8;
typedef __attribute__((ext_vector_type(8))) unsigned short ushort8;
typedef __attribute__((ext_vector_type(4))) float fx4;

constexpr int EDIM = 512;
constexpr int FDIM = 2048;
constexpr int NQ   = 10;
constexpr int BK   = 64;
constexpr int NCH  = FDIM / BK;   // 32

__device__ __forceinline__ ushort f2bf(float f) {   // f32 -> bf16 RNE
    union { float f; unsigned u; } v; v.f = f;
    unsigned u = v.u + 0x7FFFu + ((v.u >> 16) & 1u);
    return (ushort)(u >> 16);
}
__device__ __forceinline__ unsigned bits2(__hip_bfloat162 h) {
    union { __hip_bfloat162 h; unsigned u; } v; v.h = h; return v.u;
}
__device__ __forceinline__ void gload_lds16(const void* g, void* l) {
    __builtin_amdgcn_global_load_lds(
        (const __attribute__((address_space(1))) void*)g,
        (__attribute__((address_space(3))) void*)l, 16, 0, 0);
}

// ---- prep: w2 f32 -> bf16 ----
__global__ void prep(const float* __restrict__ w2, ushort* __restrict__ w2b) {
    int gid = blockIdx.x * blockDim.x + threadIdx.x;
    int np  = gridDim.x * blockDim.x;
    for (int i = gid; i < EDIM * FDIM / 4; i += np) {
        float4 v = ((const float4*)w2)[i];
        ushort4 o; o.x = f2bf(v.x); o.y = f2bf(v.y); o.z = f2bf(v.z); o.w = f2bf(v.w);
        ((ushort4*)w2b)[i] = o;
    }
}

// ---- GEMM1: h[m][f] = relu(sum_w q[m][w]*w1[f][w] + b1[f]), bf16 out ----
__global__ __launch_bounds__(256, 2) void gemm1(
    const float* __restrict__ x, const float* __restrict__ rx,
    const float* __restrict__ w1, const float* __restrict__ b1,
    ushort* __restrict__ h, int m_base)
{
    __shared__ float qs[32][NQ];
    const int tid = threadIdx.x;
    const int m0  = m_base + blockIdx.x * 32;

    if (tid < 32) {
        const float* xr = x + (size_t)(m0 + tid) * EDIM;
        float c[NQ], q[NQ];
        #pragma unroll
        for (int w = 0; w < NQ; ++w) c[w] = cosf(xr[w] + rx[w]);
        float p0 = c[1];
        #pragma unroll
        for (int w = 2; w < NQ; ++w) p0 *= c[w];
        q[0] = p0;
        float p = c[0];
        #pragma unroll
        for (int w = 1; w < NQ; ++w) { p *= c[w]; q[w] = p; }
        #pragma unroll
        for (int w = 0; w < NQ; ++w) qs[tid][w] = q[w];
    }
    __syncthreads();

    float wv[80];   // w1 rows [8t, 8t+8), contiguous 320B
    {
        const float4* wp = (const float4*)(w1 + (size_t)tid * 80);
        #pragma unroll
        for (int u = 0; u < 20; ++u) ((float4*)wv)[u] = wp[u];
    }
    float bv[8];
    {
        float4 a = *(const float4*)(b1 + tid * 8);
        float4 b = *(const float4*)(b1 + tid * 8 + 4);
        bv[0]=a.x; bv[1]=a.y; bv[2]=a.z; bv[3]=a.w;
        bv[4]=b.x; bv[5]=b.y; bv[6]=b.z; bv[7]=b.w;
    }
    ushort* hrow = h + (size_t)m0 * FDIM + tid * 8;

    for (int m = 0; m < 32; ++m) {
        float qv[NQ];
        #pragma unroll
        for (int w = 0; w < NQ; ++w) qv[w] = qs[m][w];
        float a[8];
        #pragma unroll
        for (int r = 0; r < 8; ++r) a[r] = bv[r];
        #pragma unroll
        for (int w = 0; w < NQ; ++w)
            #pragma unroll
            for (int r = 0; r < 8; ++r)
                a[r] = fmaf(qv[w], wv[r * 10 + w], a[r]);
        ushort8 o;
        #pragma unroll
        for (int r = 0; r < 4; ++r) {
            unsigned p = bits2(__float22bfloat162_rn(
                make_float2(fmaxf(a[2*r], 0.f), fmaxf(a[2*r+1], 0.f))));
            o[2*r]   = (ushort)(p & 0xFFFFu);
            o[2*r+1] = (ushort)(p >> 16);
        }
        *(ushort8*)(hrow + (size_t)m * FDIM) = o;
    }
}

// ---- GEMM2: out = h @ w2^T + b2 ----
// Tile LDS layout: [row][k], BK=64 (128B rows), 16B block bs within a row
// stores logical k-block bl = bs ^ (row&7). Staged chunk c = u*256+tid:
// row = u*32 + (tid>>3), bs = tid&7 -> lane fetches global k-block bs^(row&7).
__global__ __launch_bounds__(256, 2) void gemm2(
    const ushort* __restrict__ h,     // [M][FDIM] bf16
    const ushort* __restrict__ w2b,   // [EDIM][FDIM] bf16
    const float* __restrict__ b2,
    float* __restrict__ out, int m_base)
{
    __shared__ ushort As[128 * BK];   // 16 KB
    __shared__ ushort Bs[128 * BK];   // 16 KB

    const int tid  = threadIdx.x;
    const int bm   = blockIdx.x;      // fast-varying -> twins (same bm) on same XCD
    const int bn   = blockIdx.y;
    const int m0   = m_base + bm * 128, n0 = bn * 128;
    const int wave = tid >> 6, lane = tid & 63;
    const int quad = lane >> 4, l16 = lane & 15;
    const int wm   = wave >> 1, wn = wave & 1;

    // staging: 4 chunks per tile per thread
    const int srow0 = tid >> 3;               // + u*32
    const int sbs   = tid & 7;
    const ushort* gA[4]; const ushort* gB[4];
    #pragma unroll
    for (int u = 0; u < 4; ++u) {
        int row = u * 32 + srow0;
        int bl  = sbs ^ (row & 7);
        gA[u] = h   + (size_t)(m0 + row) * FDIM + bl * 8;
        gB[u] = w2b + (size_t)(n0 + row) * FDIM + bl * 8;
    }
    const int ldst = wave * 512;              // + u*2048, ushorts

    // frag-read offsets: row' = (wm|wn)*64 + mt*16 + l16; swz = l16&7
    const int swz = l16 & 7;
    int aro[4], bro[4];
    #pragma unroll
    for (int t = 0; t < 4; ++t) {
        aro[t] = (wm * 64 + t * 16 + l16) * BK;
        bro[t] = (wn * 64 + t * 16 + l16) * BK;
    }

    fx4 acc[4][4];
    #pragma unroll
    for (int a = 0; a < 4; ++a)
        #pragma unroll
        for (int b = 0; b < 4; ++b) acc[a][b] = fx4{0.f, 0.f, 0.f, 0.f};

    for (int i = 0; i < NCH; ++i) {
        #pragma unroll
        for (int u = 0; u < 4; ++u) {
            gload_lds16(gA[u], &As[u * 2048 + ldst]);
            gload_lds16(gB[u], &Bs[u * 2048 + ldst]);
            gA[u] += BK; gB[u] += BK;
        }
        __syncthreads();                       // tiles ready (vmcnt drain)

        short8 af[4][2], bf[4][2];
        #pragma unroll
        for (int t = 0; t < 4; ++t)
            #pragma unroll
            for (int hf = 0; hf < 2; ++hf) {
                const int blk = (hf * 4 + quad) ^ swz;
                af[t][hf] = *(const short8*)&As[aro[t] + blk * 8];
                bf[t][hf] = *(const short8*)&Bs[bro[t] + blk * 8];
            }

        #pragma unroll
        for (int hf = 0; hf < 2; ++hf)
            #pragma unroll
            for (int mt = 0; mt < 4; ++mt)
                #pragma unroll
                for (int nt = 0; nt < 4; ++nt)
                    acc[mt][nt] = __builtin_amdgcn_mfma_f32_16x16x32_bf16(
                        af[mt][hf], bf[nt][hf], acc[mt][nt], 0, 0, 0);
        __syncthreads();                       // protect tiles from next stage
    }

    // epilogue: + b2, C-layout (col=l16 -> n, row=quad*4+r -> m)
    float bb[4];
    #pragma unroll
    for (int nt = 0; nt < 4; ++nt) bb[nt] = b2[n0 + wn * 64 + nt * 16 + l16];
    #pragma unroll
    for (int mt = 0; mt < 4; ++mt) {
        const int mbase = m0 + wm * 64 + mt * 16 + quad * 4;
        #pragma unroll
        for (int nt = 0; nt < 4; ++nt) {
            const int n = n0 + wn * 64 + nt * 16 + l16;
            #pragma unroll
            for (int r = 0; r < 4; ++r)
                out[(size_t)(mbase + r) * EDIM + n] = acc[mt][nt][r] + bb[nt];
        }
    }
}

extern "C" void kernel_launch(void* const* d_in, const int* in_sizes, int n_in,
                              void* d_out, int out_size, void* d_ws, size_t ws_size,
                              hipStream_t stream) {
    const float* x  = (const float*)d_in[0];
    const float* rx = (const float*)d_in[1];
    const float* w1 = (const float*)d_in[2];
    const float* b1 = (const float*)d_in[3];
    const float* w2 = (const float*)d_in[4];
    const float* b2 = (const float*)d_in[5];
    float* out = (float*)d_out;

    const int M = in_sizes[0] / EDIM;   // 16384

    const size_t w2bytes = (size_t)EDIM * FDIM * 2;
    ushort* w2b = (ushort*)d_ws;
    ushort* h   = (ushort*)((char*)d_ws + w2bytes);

    int Ms = M;   // slice if ws can't hold full h (full M needs 64 MiB)
    {
        size_t avail = (ws_size > w2bytes) ? ws_size - w2bytes : 0;
        int cap = (int)(avail / ((size_t)FDIM * 2));
        cap &= ~127;
        if (cap < 128) cap = 128;
        if (Ms > cap) Ms = cap;
    }

    hipLaunchKernelGGL(prep, dim3(256), dim3(256), 0, stream, w2, w2b);

    for (int mb = 0; mb < M; mb += Ms) {
        int cur = (M - mb < Ms) ? (M - mb) : Ms;
        hipLaunchKernelGGL(gemm1, dim3(cur / 32), dim3(256), 0, stream,
                           x, rx, w1, b1, h, mb);
        hipLaunchKernelGGL(gemm2, dim3(cur / 128, 4), dim3(256), 0, stream,
                           h, w2b, b2, out, mb);
    }
}